// Round 4
// baseline (2997.907 us; speedup 1.0000x reference)
//
#include <hip/hip_runtime.h>
#include <stdint.h>

#define D_MODEL 1024
#define D_HID   4096
#define NEXP    8
#define NTOK    8192
#define TOTROW  (NTOK*2)

typedef unsigned short ushort_t;
typedef __attribute__((ext_vector_type(8))) short short8;
typedef __attribute__((ext_vector_type(4))) float f32x4;

static __device__ __forceinline__ ushort_t f2bf(float f) {
    union { float f; uint32_t u; } v; v.f = f;
    uint32_t u = v.u;
    uint32_t r = (u + 0x7FFFu + ((u >> 16) & 1u)) >> 16;
    return (ushort_t)r;
}
static __device__ __forceinline__ float bf2f(ushort_t h) {
    union { uint32_t u; float f; } v; v.u = ((uint32_t)h) << 16;
    return v.f;
}
static __device__ __forceinline__ float gelu_f(float x) {
    return 0.5f * x * (1.0f + erff(x * 0.70710678118654752f));
}

static __device__ __forceinline__ void gload_lds16(const void* g, void* l) {
    __builtin_amdgcn_global_load_lds(
        (const __attribute__((address_space(1))) void*)g,
        (__attribute__((address_space(3))) void*)l,
        16, 0, 0);
}

// ---------------- router ----------------
__global__ __launch_bounds__(256) void router_kernel(
    const float* __restrict__ x, const float* __restrict__ et,
    int* __restrict__ cnt, int* __restrict__ top2)
{
    __shared__ float lds_et[NEXP * D_MODEL];
    int t = threadIdx.x;
    #pragma unroll
    for (int i = 0; i < (NEXP * D_MODEL) / 256; ++i)
        lds_et[i * 256 + t] = et[i * 256 + t];
    __syncthreads();

    int lane = t & 63, wv = t >> 6;
    int n = blockIdx.x * 4 + wv;
    double s[NEXP];
    #pragma unroll
    for (int e = 0; e < NEXP; ++e) s[e] = 0.0;
    const float* xr = x + (size_t)n * D_MODEL;
    for (int it = 0; it < D_MODEL / 64; ++it) {
        float xv = xr[it * 64 + lane];
        #pragma unroll
        for (int e = 0; e < NEXP; ++e)
            s[e] += (double)(xv * lds_et[e * D_MODEL + it * 64 + lane]);
    }
    #pragma unroll
    for (int e = 0; e < NEXP; ++e)
        for (int off = 32; off; off >>= 1)
            s[e] += __shfl_xor(s[e], off);

    if (lane == 0) {
        int e1 = 0;
        for (int e = 1; e < NEXP; ++e) if (s[e] > s[e1]) e1 = e;
        int e2 = (e1 == 0) ? 1 : 0;
        for (int e = 0; e < NEXP; ++e) if (e != e1 && s[e] > s[e2]) e2 = e;
        top2[n * 2 + 0] = e1;
        top2[n * 2 + 1] = e2;
        atomicAdd(&cnt[e1], 1);
        atomicAdd(&cnt[e2], 1);
    }
}

__global__ void scan_kernel(const int* __restrict__ cnt, int* __restrict__ base,
                            int* __restrict__ cnt2)
{
    if (threadIdx.x == 0 && blockIdx.x == 0) {
        int acc = 0;
        for (int e = 0; e < NEXP; ++e) { base[e] = acc; acc += cnt[e]; cnt2[e] = 0; }
    }
}

__global__ __launch_bounds__(256) void assign_kernel(
    const int* __restrict__ top2, const int* __restrict__ base,
    int* __restrict__ cnt2, int* __restrict__ rowinfo, int* __restrict__ token_rows)
{
    int n = blockIdx.x * 256 + threadIdx.x;
    if (n >= NTOK) return;
    #pragma unroll
    for (int k = 0; k < 2; ++k) {
        int e = top2[n * 2 + k];
        int slot = atomicAdd(&cnt2[e], 1);
        int row = base[e] + slot;
        rowinfo[row] = n;
        token_rows[n * 2 + k] = row;
    }
}

// ---------------- x fp32 -> bf16 ----------------
__global__ __launch_bounds__(256) void convert_x(
    const float* __restrict__ x, ushort_t* __restrict__ xb)
{
    size_t i = ((size_t)blockIdx.x * 256 + threadIdx.x) * 4;
    float4 f = *(const float4*)(x + i);
    ushort_t o[4];
    o[0] = f2bf(f.x); o[1] = f2bf(f.y); o[2] = f2bf(f.z); o[3] = f2bf(f.w);
    *(uint2*)(xb + i) = *(const uint2*)o;
}

// ------------- weight transpose+convert: [E][K][N] f32 -> [E][N][K] bf16 -------------
// 64x64 tiles, float4 loads, ushort8 stores (all bank patterns 2-way = free).
__global__ __launch_bounds__(256) void transpose_kernel(
    const float* __restrict__ in, ushort_t* __restrict__ out, int K, int N)
{
    __shared__ float tile[64][65];
    int e = blockIdx.z;
    int k0 = blockIdx.y * 64, n0 = blockIdx.x * 64;
    const float* ine = in + (size_t)e * K * N + (size_t)k0 * N + n0;
    ushort_t* oute = out + (size_t)e * N * K + (size_t)n0 * K + k0;
    int t = threadIdx.x;
    int lr = t >> 4;          // 0..15
    int lc = (t & 15) * 4;    // 0..60
    #pragma unroll
    for (int i = 0; i < 4; ++i) {
        float4 v = *(const float4*)(ine + (size_t)(i * 16 + lr) * N + lc);
        tile[i * 16 + lr][lc + 0] = v.x;
        tile[i * 16 + lr][lc + 1] = v.y;
        tile[i * 16 + lr][lc + 2] = v.z;
        tile[i * 16 + lr][lc + 3] = v.w;
    }
    __syncthreads();
    int nr = t >> 3;          // 0..31
    int kg = (t & 7) * 8;     // 0..56
    #pragma unroll
    for (int j = 0; j < 2; ++j) {
        int n = j * 32 + nr;
        ushort_t o[8];
        #pragma unroll
        for (int m = 0; m < 8; ++m) o[m] = f2bf(tile[kg + m][n]);
        *(uint4*)(oute + (size_t)n * K + kg) = *(const uint4*)o;
    }
}

// ================= grouped GEMM: 256x256 tile, BK=64, 8-phase, read-ahead =================
// LDS[buf][row][slot]: slot s holds global k-slot s^(row&7) (source pre-swizzle, linear dest).
// Quadrant order per buffer: (0,0)(0,1)(1,0)(1,1) -> all fragment sets single-buffered.
// Each phase: {ds_read regs for NEXT quadrant | stage one 16KB unit | sched_barrier |
//              s_barrier | MFMA current quadrant (regs loaded LAST phase; compiler
//              inserts counted lgkm waits) | s_barrier}.
// vmcnt(2) sits in the read-free phases' tails (ph3/ph7) BEFORE the end-barrier, so the
// barrier publishes "all waves' staged units through ph2/ph6 have landed" to the
// cross-wave readers in ph4/ph8. Final iteration uses vmcnt(0) at ph3-tail.

#define RD_A(DST, BUF, MH) do {                                                  \
    _Pragma("unroll") for (int mi = 0; mi < 4; ++mi)                             \
    _Pragma("unroll") for (int ks = 0; ks < 2; ++ks)                             \
        DST[mi][ks] = *(const short8*)&As[BUF][wm*128 + (MH)*64 + mi*16 + l15][((ks*4 + lhi) ^ key) * 8]; \
} while (0)

#define RD_B(DST, BUF, NH) do {                                                  \
    _Pragma("unroll") for (int ni = 0; ni < 2; ++ni)                             \
    _Pragma("unroll") for (int ks = 0; ks < 2; ++ks)                             \
        DST[ni][ks] = *(const short8*)&Bs[BUF][wn*64 + (NH)*32 + ni*16 + l15][((ks*4 + lhi) ^ key) * 8]; \
} while (0)

#define MM(AR, BR, MH, NH) do {                                                  \
    __builtin_amdgcn_s_setprio(1);                                               \
    _Pragma("unroll") for (int mi = 0; mi < 4; ++mi)                             \
    _Pragma("unroll") for (int ni = 0; ni < 2; ++ni)                             \
    _Pragma("unroll") for (int ks = 0; ks < 2; ++ks)                             \
        acc[(MH)*4 + mi][(NH)*2 + ni] = __builtin_amdgcn_mfma_f32_16x16x32_bf16( \
            AR[mi][ks], BR[ni][ks], acc[(MH)*4 + mi][(NH)*2 + ni], 0, 0, 0);     \
    __builtin_amdgcn_s_setprio(0);                                               \
} while (0)

#define SBAR __builtin_amdgcn_s_barrier()
#define SCH0 __builtin_amdgcn_sched_barrier(0)
#define VW2  asm volatile("s_waitcnt vmcnt(2)" ::: "memory")
#define VW0  asm volatile("s_waitcnt vmcnt(0)" ::: "memory")

template<bool GATHER, bool GELU_ACT>
__global__ __launch_bounds__(512, 2) void moe_gemm8(
    const ushort_t* __restrict__ Ah,
    const ushort_t* __restrict__ BT,
    const float* __restrict__ bias,
    ushort_t* __restrict__ C,
    const int* __restrict__ cnt, const int* __restrict__ basep,
    const int* __restrict__ rowinfo,
    int Ncols, int K)
{
    const int e = blockIdx.z;
    const int cnte = cnt[e];
    const int mt = blockIdx.y;
    if (mt * 256 >= cnte) return;
    const int base_e = basep[e];
    const int row0 = base_e + mt * 256;
    const int col0 = blockIdx.x * 256;

    __shared__ __attribute__((aligned(16))) ushort_t As[2][256][64]; // 64 KB
    __shared__ __attribute__((aligned(16))) ushort_t Bs[2][256][64]; // 64 KB

    const int t = threadIdx.x;
    const int lane = t & 63;
    const int wv = t >> 6;       // 0..7
    const int wm = wv >> 2;      // 0..1
    const int wn = wv & 3;       // 0..3
    const int l15 = lane & 15, lhi = lane >> 4;
    const int key = l15 & 7;
    const int lr8 = lane >> 3;                 // 0..7
    const int sl  = (lane & 7) ^ lr8;          // pre-swizzled global k-slot

    // staging source byte-offsets (u32; max buffer 268 MB)
    uint32_t aOff[2][2], bOff[2][2];
    #pragma unroll
    for (int mh = 0; mh < 2; ++mh)
        #pragma unroll
        for (int c = 0; c < 2; ++c) {
            int tr = mh * 64 + wv * 8 + lr8 + c * 128;
            int gr = row0 + tr; if (gr > TOTROW - 1) gr = TOTROW - 1;
            uint32_t rowid = GATHER ? (uint32_t)rowinfo[gr] : (uint32_t)gr;
            aOff[mh][c] = rowid * (uint32_t)(K * 2) + sl * 16;
        }
    #pragma unroll
    for (int nh = 0; nh < 2; ++nh)
        #pragma unroll
        for (int c = 0; c < 2; ++c) {
            int tr = (wv >> 2) * 64 + nh * 32 + (wv & 3) * 8 + lr8 + c * 128;
            bOff[nh][c] = ((uint32_t)e * Ncols + col0 + tr) * (uint32_t)(K * 2) + sl * 16;
        }

    const int arb = wv * 8;                               // A LDS row base (+mh*64, +128 for c=1)
    const int brb = (wv >> 2) * 64 + (wv & 3) * 8;        // B LDS row base (+nh*32, +128 for c=1)

    auto stageA = [&](int buf, int mh, int kt) {
        gload_lds16((const char*)Ah + aOff[mh][0] + kt * 128, (void*)&As[buf][mh * 64 + arb][0]);
        gload_lds16((const char*)Ah + aOff[mh][1] + kt * 128, (void*)&As[buf][128 + mh * 64 + arb][0]);
    };
    auto stageB = [&](int buf, int nh, int kt) {
        gload_lds16((const char*)BT + bOff[nh][0] + kt * 128, (void*)&Bs[buf][nh * 32 + brb][0]);
        gload_lds16((const char*)BT + bOff[nh][1] + kt * 128, (void*)&Bs[buf][128 + nh * 32 + brb][0]);
    };

    f32x4 acc[8][4];
    #pragma unroll
    for (int i = 0; i < 8; ++i)
        #pragma unroll
        for (int j = 0; j < 4; ++j)
            acc[i][j] = (f32x4){0.f, 0.f, 0.f, 0.f};

    short8 aregA[4][2], aregB[4][2], breg0[2][2], bregN1[2][2];

    const int KT = K / 64;
    const int NIT = KT / 2;

    // prologue: buf0 kt0 fully; buf1 kt1 units A-mh0, B-nh1 (the "prev-ph7/ph8" units)
    stageA(0, 0, 0); stageA(0, 1, 0); stageB(0, 0, 0); stageB(0, 1, 0);
    stageA(1, 0, 1); stageB(1, 1, 1);
    asm volatile("s_waitcnt vmcnt(4)" ::: "memory");   // buf0 landed (own loads)
    SBAR;                                              // publish across waves
    RD_A(aregA, 0, 0); RD_B(breg0, 0, 0);              // regs for ph1
    SCH0;

    for (int i2 = 0; i2 < NIT - 1; ++i2) {
        const int kt1 = 2 * i2 + 1, kt2 = 2 * i2 + 2, kt3 = 2 * i2 + 3;
        /*ph1*/ RD_B(bregN1, 0, 1);                   stageA(1, 1, kt1); SCH0; SBAR; MM(aregA, breg0,  0, 0);      SBAR;
        /*ph2*/ RD_A(aregB, 0, 1);                    stageB(1, 0, kt1); SCH0; SBAR; MM(aregA, bregN1, 0, 1);      SBAR;
        /*ph3*/                                       stageA(0, 0, kt2); SCH0; SBAR; MM(aregB, breg0,  1, 0); VW2; SBAR;
        /*ph4*/ RD_A(aregA, 1, 0); RD_B(breg0, 1, 0); stageB(0, 1, kt2); SCH0; SBAR; MM(aregB, bregN1, 1, 1);      SBAR;
        /*ph5*/ RD_B(bregN1, 1, 1);                   stageA(0, 1, kt2); SCH0; SBAR; MM(aregA, breg0,  0, 0);      SBAR;
        /*ph6*/ RD_A(aregB, 1, 1);                    stageB(0, 0, kt2); SCH0; SBAR; MM(aregA, bregN1, 0, 1);      SBAR;
        /*ph7*/                                       stageA(1, 0, kt3); SCH0; SBAR; MM(aregB, breg0,  1, 0); VW2; SBAR;
        /*ph8*/ RD_A(aregA, 0, 0); RD_B(breg0, 0, 0); stageB(1, 1, kt3); SCH0; SBAR; MM(aregB, bregN1, 1, 1);      SBAR;
    }
    {   // final iteration: no kt2/kt3 staging; full drain at ph3-tail
        const int kt1 = 2 * (NIT - 1) + 1;
        /*f1*/ RD_B(bregN1, 0, 1);                   stageA(1, 1, kt1); SCH0; SBAR; MM(aregA, breg0,  0, 0);      SBAR;
        /*f2*/ RD_A(aregB, 0, 1);                    stageB(1, 0, kt1); SCH0; SBAR; MM(aregA, bregN1, 0, 1);      SBAR;
        /*f3*/                                                                SBAR; MM(aregB, breg0,  1, 0); VW0; SBAR;
        /*f4*/ RD_A(aregA, 1, 0); RD_B(breg0, 1, 0);                    SCH0; SBAR; MM(aregB, bregN1, 1, 1);      SBAR;
        /*f5*/ RD_B(bregN1, 1, 1);                                      SCH0; SBAR; MM(aregA, breg0,  0, 0);      SBAR;
        /*f6*/ RD_A(aregB, 1, 1);                                       SCH0; SBAR; MM(aregA, bregN1, 0, 1);      SBAR;
        /*f7*/                                                                SBAR; MM(aregB, breg0,  1, 0);      SBAR;
        /*f8*/                                                                      MM(aregB, bregN1, 1, 1);
    }

    // epilogue: C/D layout col=lane&15, row=(lane>>4)*4+q
    #pragma unroll
    for (int n = 0; n < 4; ++n) {
        int colg = col0 + wn * 64 + n * 16 + l15;
        float bv = bias[e * Ncols + colg];
        #pragma unroll
        for (int m = 0; m < 8; ++m) {
            #pragma unroll
            for (int q = 0; q < 4; ++q) {
                int rl = mt * 256 + wm * 128 + m * 16 + lhi * 4 + q;
                if (rl < cnte) {
                    float v = acc[m][n][q] + bv;
                    if (GELU_ACT) v = gelu_f(v);
                    C[(size_t)(base_e + rl) * Ncols + colg] = f2bf(v);
                }
            }
        }
    }
}

// ---------------- combine: out[n] = 0.5*(Y[r1] + Y[r2]) ----------------
__global__ __launch_bounds__(256) void combine_kernel(
    const ushort_t* __restrict__ Y, const int* __restrict__ token_rows,
    float* __restrict__ out)
{
    int n = blockIdx.x;
    int t = threadIdx.x;
    int r1 = token_rows[n * 2 + 0], r2 = token_rows[n * 2 + 1];
    const ushort_t* y1 = Y + (size_t)r1 * D_MODEL + t * 4;
    const ushort_t* y2 = Y + (size_t)r2 * D_MODEL + t * 4;
    ushort_t a[4], b[4];
    *(uint2*)a = *(const uint2*)y1;
    *(uint2*)b = *(const uint2*)y2;
    float4 o;
    o.x = 0.5f * (bf2f(a[0]) + bf2f(b[0]));
    o.y = 0.5f * (bf2f(a[1]) + bf2f(b[1]));
    o.z = 0.5f * (bf2f(a[2]) + bf2f(b[2]));
    o.w = 0.5f * (bf2f(a[3]) + bf2f(b[3]));
    *(float4*)(out + (size_t)n * D_MODEL + t * 4) = o;
}

extern "C" void kernel_launch(void* const* d_in, const int* in_sizes, int n_in,
                              void* d_out, int out_size, void* d_ws, size_t ws_size,
                              hipStream_t stream)
{
    const float* x  = (const float*)d_in[0];
    const float* et = (const float*)d_in[1];
    const float* W1 = (const float*)d_in[2];
    const float* b1 = (const float*)d_in[3];
    const float* W2 = (const float*)d_in[4];
    const float* b2 = (const float*)d_in[5];
    const float* W3 = (const float*)d_in[6];
    const float* b3 = (const float*)d_in[7];
    float* out = (float*)d_out;

    char* ws = (char*)d_ws;
    size_t off = 0;
    auto alloc = [&](size_t bytes) -> char* {
        char* p = ws + off;
        off += (bytes + 255) & ~(size_t)255;
        return p;
    };
    int* cnt        = (int*)alloc(NEXP * 4);
    int* basep      = (int*)alloc(NEXP * 4);
    int* cnt2       = (int*)alloc(NEXP * 4);
    int* top2       = (int*)alloc((size_t)NTOK * 2 * 4);
    int* token_rows = (int*)alloc((size_t)NTOK * 2 * 4);
    int* rowinfo    = (int*)alloc((size_t)TOTROW * 4);
    ushort_t* W1T = (ushort_t*)alloc((size_t)NEXP * D_HID * D_MODEL * 2);
    ushort_t* W2T = (ushort_t*)alloc((size_t)NEXP * D_HID * D_HID * 2);
    ushort_t* W3T = (ushort_t*)alloc((size_t)NEXP * D_MODEL * D_HID * 2);
    ushort_t* H1  = (ushort_t*)alloc((size_t)TOTROW * D_HID * 2);
    ushort_t* H2  = (ushort_t*)alloc((size_t)TOTROW * D_HID * 2);
    ushort_t* Yr  = (ushort_t*)alloc((size_t)TOTROW * D_MODEL * 2);
    if (off > ws_size) return; // workspace too small: fail loudly (wrong output)

    // xb (bf16 x) aliases H2: dead until GEMM2 writes H2.
    ushort_t* xb = H2;

    hipMemsetAsync(cnt, 0, NEXP * 4, stream);
    router_kernel<<<NTOK / 4, 256, 0, stream>>>(x, et, cnt, top2);
    scan_kernel<<<1, 64, 0, stream>>>(cnt, basep, cnt2);
    assign_kernel<<<NTOK / 256, 256, 0, stream>>>(top2, basep, cnt2, rowinfo, token_rows);

    convert_x<<<(NTOK * D_MODEL) / 1024, 256, 0, stream>>>(x, xb);

    transpose_kernel<<<dim3(D_HID / 64, D_MODEL / 64, NEXP), 256, 0, stream>>>(W1, W1T, D_MODEL, D_HID);
    transpose_kernel<<<dim3(D_HID / 64, D_HID / 64, NEXP), 256, 0, stream>>>(W2, W2T, D_HID, D_HID);
    transpose_kernel<<<dim3(D_MODEL / 64, D_HID / 64, NEXP), 256, 0, stream>>>(W3, W3T, D_HID, D_MODEL);

    moe_gemm8<true, true><<<dim3(D_HID / 256, 16, NEXP), 512, 0, stream>>>(
        xb, W1T, b1, H1, cnt, basep, rowinfo, D_HID, D_MODEL);
    moe_gemm8<false, true><<<dim3(D_HID / 256, 16, NEXP), 512, 0, stream>>>(
        H1, W2T, b2, H2, cnt, basep, rowinfo, D_HID, D_HID);
    moe_gemm8<false, false><<<dim3(D_MODEL / 256, 16, NEXP), 512, 0, stream>>>(
        H2, W3T, b3, Yr, cnt, basep, rowinfo, D_MODEL, D_HID);

    combine_kernel<<<NTOK, 256, 0, stream>>>(Yr, token_rows, out);
}

// Round 5
// 2991.142 us; speedup vs baseline: 1.0023x; 1.0023x over previous
//
#include <hip/hip_runtime.h>
#include <stdint.h>

#define D_MODEL 1024
#define D_HID   4096
#define NEXP    8
#define NTOK    8192
#define TOTROW  (NTOK*2)

typedef unsigned short ushort_t;
typedef __attribute__((ext_vector_type(8))) short short8;
typedef __attribute__((ext_vector_type(4))) float f32x4;

static __device__ __forceinline__ ushort_t f2bf(float f) {
    union { float f; uint32_t u; } v; v.f = f;
    uint32_t u = v.u;
    uint32_t r = (u + 0x7FFFu + ((u >> 16) & 1u)) >> 16;
    return (ushort_t)r;
}
static __device__ __forceinline__ float bf2f(ushort_t h) {
    union { uint32_t u; float f; } v; v.u = ((uint32_t)h) << 16;
    return v.f;
}
static __device__ __forceinline__ float gelu_f(float x) {
    return 0.5f * x * (1.0f + erff(x * 0.70710678118654752f));
}

static __device__ __forceinline__ void gload_lds16(const void* g, void* l) {
    __builtin_amdgcn_global_load_lds(
        (const __attribute__((address_space(1))) void*)g,
        (__attribute__((address_space(3))) void*)l,
        16, 0, 0);
}

// ---------------- router ----------------
__global__ __launch_bounds__(256) void router_kernel(
    const float* __restrict__ x, const float* __restrict__ et,
    int* __restrict__ cnt, int* __restrict__ top2)
{
    __shared__ float lds_et[NEXP * D_MODEL];
    int t = threadIdx.x;
    #pragma unroll
    for (int i = 0; i < (NEXP * D_MODEL) / 256; ++i)
        lds_et[i * 256 + t] = et[i * 256 + t];
    __syncthreads();

    int lane = t & 63, wv = t >> 6;
    int n = blockIdx.x * 4 + wv;
    double s[NEXP];
    #pragma unroll
    for (int e = 0; e < NEXP; ++e) s[e] = 0.0;
    const float* xr = x + (size_t)n * D_MODEL;
    for (int it = 0; it < D_MODEL / 64; ++it) {
        float xv = xr[it * 64 + lane];
        #pragma unroll
        for (int e = 0; e < NEXP; ++e)
            s[e] += (double)(xv * lds_et[e * D_MODEL + it * 64 + lane]);
    }
    #pragma unroll
    for (int e = 0; e < NEXP; ++e)
        for (int off = 32; off; off >>= 1)
            s[e] += __shfl_xor(s[e], off);

    if (lane == 0) {
        int e1 = 0;
        for (int e = 1; e < NEXP; ++e) if (s[e] > s[e1]) e1 = e;
        int e2 = (e1 == 0) ? 1 : 0;
        for (int e = 0; e < NEXP; ++e) if (e != e1 && s[e] > s[e2]) e2 = e;
        top2[n * 2 + 0] = e1;
        top2[n * 2 + 1] = e2;
        atomicAdd(&cnt[e1], 1);
        atomicAdd(&cnt[e2], 1);
    }
}

__global__ void scan_kernel(const int* __restrict__ cnt, int* __restrict__ base,
                            int* __restrict__ cnt2)
{
    if (threadIdx.x == 0 && blockIdx.x == 0) {
        int acc = 0;
        for (int e = 0; e < NEXP; ++e) { base[e] = acc; acc += cnt[e]; cnt2[e] = 0; }
    }
}

__global__ __launch_bounds__(256) void assign_kernel(
    const int* __restrict__ top2, const int* __restrict__ base,
    int* __restrict__ cnt2, int* __restrict__ rowinfo, int* __restrict__ token_rows)
{
    int n = blockIdx.x * 256 + threadIdx.x;
    if (n >= NTOK) return;
    #pragma unroll
    for (int k = 0; k < 2; ++k) {
        int e = top2[n * 2 + k];
        int slot = atomicAdd(&cnt2[e], 1);
        int row = base[e] + slot;
        rowinfo[row] = n;
        token_rows[n * 2 + k] = row;
    }
}

// ---------------- x fp32 -> bf16 ----------------
__global__ __launch_bounds__(256) void convert_x(
    const float* __restrict__ x, ushort_t* __restrict__ xb)
{
    size_t i = ((size_t)blockIdx.x * 256 + threadIdx.x) * 4;
    float4 f = *(const float4*)(x + i);
    ushort_t o[4];
    o[0] = f2bf(f.x); o[1] = f2bf(f.y); o[2] = f2bf(f.z); o[3] = f2bf(f.w);
    *(uint2*)(xb + i) = *(const uint2*)o;
}

// ------------- weight transpose+convert: [E][K][N] f32 -> [E][N][K] bf16 -------------
// 64x64 tiles, float4 loads, ushort8 stores (all bank patterns 2-way = free).
__global__ __launch_bounds__(256) void transpose_kernel(
    const float* __restrict__ in, ushort_t* __restrict__ out, int K, int N)
{
    __shared__ float tile[64][65];
    int e = blockIdx.z;
    int k0 = blockIdx.y * 64, n0 = blockIdx.x * 64;
    const float* ine = in + (size_t)e * K * N + (size_t)k0 * N + n0;
    ushort_t* oute = out + (size_t)e * N * K + (size_t)n0 * K + k0;
    int t = threadIdx.x;
    int lr = t >> 4;          // 0..15
    int lc = (t & 15) * 4;    // 0..60
    #pragma unroll
    for (int i = 0; i < 4; ++i) {
        float4 v = *(const float4*)(ine + (size_t)(i * 16 + lr) * N + lc);
        tile[i * 16 + lr][lc + 0] = v.x;
        tile[i * 16 + lr][lc + 1] = v.y;
        tile[i * 16 + lr][lc + 2] = v.z;
        tile[i * 16 + lr][lc + 3] = v.w;
    }
    __syncthreads();
    int nr = t >> 3;          // 0..31
    int kg = (t & 7) * 8;     // 0..56
    #pragma unroll
    for (int j = 0; j < 2; ++j) {
        int n = j * 32 + nr;
        ushort_t o[8];
        #pragma unroll
        for (int m = 0; m < 8; ++m) o[m] = f2bf(tile[kg + m][n]);
        *(uint4*)(oute + (size_t)n * K + kg) = *(const uint4*)o;
    }
}

// ================= grouped GEMM: 256x256 tile, BK=64, 8-phase, read-ahead =================
// LDS[buf][row][slot]: slot s holds global k-slot s^(row&7) (source pre-swizzle, linear dest).
// Quadrant order per buffer: (0,0)(0,1)(1,0)(1,1) -> all fragment sets single-buffered.
// Each phase: {ds_read regs for NEXT quadrant | stage one 16KB unit | sched_barrier |
//              s_barrier | MFMA current quadrant (regs loaded LAST phase; compiler
//              inserts counted lgkm waits) | s_barrier}.
// vmcnt(2) sits in the read-free phases' tails (ph3/ph7) BEFORE the end-barrier, so the
// barrier publishes "all waves' staged units through ph2/ph6 have landed" to the
// cross-wave readers in ph4/ph8. Final iteration uses vmcnt(0) at ph3-tail.
// NOTE: LDS=128KB -> exactly 1 block/CU. __launch_bounds__(512,1): VGPR budget 256
// (live set ~240: acc 128 + fragments 96 + staging offsets/temps). (512,2) capped
// VGPRs at 128 -> ~800MB of scratch spill traffic per GEMM2 dispatch (round 4).

#define RD_A(DST, BUF, MH) do {                                                  \
    _Pragma("unroll") for (int mi = 0; mi < 4; ++mi)                             \
    _Pragma("unroll") for (int ks = 0; ks < 2; ++ks)                             \
        DST[mi][ks] = *(const short8*)&As[BUF][wm*128 + (MH)*64 + mi*16 + l15][((ks*4 + lhi) ^ key) * 8]; \
} while (0)

#define RD_B(DST, BUF, NH) do {                                                  \
    _Pragma("unroll") for (int ni = 0; ni < 2; ++ni)                             \
    _Pragma("unroll") for (int ks = 0; ks < 2; ++ks)                             \
        DST[ni][ks] = *(const short8*)&Bs[BUF][wn*64 + (NH)*32 + ni*16 + l15][((ks*4 + lhi) ^ key) * 8]; \
} while (0)

#define MM(AR, BR, MH, NH) do {                                                  \
    __builtin_amdgcn_s_setprio(1);                                               \
    _Pragma("unroll") for (int mi = 0; mi < 4; ++mi)                             \
    _Pragma("unroll") for (int ni = 0; ni < 2; ++ni)                             \
    _Pragma("unroll") for (int ks = 0; ks < 2; ++ks)                             \
        acc[(MH)*4 + mi][(NH)*2 + ni] = __builtin_amdgcn_mfma_f32_16x16x32_bf16( \
            AR[mi][ks], BR[ni][ks], acc[(MH)*4 + mi][(NH)*2 + ni], 0, 0, 0);     \
    __builtin_amdgcn_s_setprio(0);                                               \
} while (0)

#define SBAR __builtin_amdgcn_s_barrier()
#define SCH0 __builtin_amdgcn_sched_barrier(0)
#define VW2  asm volatile("s_waitcnt vmcnt(2)" ::: "memory")
#define VW0  asm volatile("s_waitcnt vmcnt(0)" ::: "memory")

template<bool GATHER, bool GELU_ACT>
__global__ __launch_bounds__(512, 1) void moe_gemm8(
    const ushort_t* __restrict__ Ah,
    const ushort_t* __restrict__ BT,
    const float* __restrict__ bias,
    ushort_t* __restrict__ C,
    const int* __restrict__ cnt, const int* __restrict__ basep,
    const int* __restrict__ rowinfo,
    int Ncols, int K)
{
    const int e = blockIdx.z;
    const int cnte = cnt[e];
    const int mt = blockIdx.y;
    if (mt * 256 >= cnte) return;
    const int base_e = basep[e];
    const int row0 = base_e + mt * 256;
    const int col0 = blockIdx.x * 256;

    __shared__ __attribute__((aligned(16))) ushort_t As[2][256][64]; // 64 KB
    __shared__ __attribute__((aligned(16))) ushort_t Bs[2][256][64]; // 64 KB

    const int t = threadIdx.x;
    const int lane = t & 63;
    const int wv = t >> 6;       // 0..7
    const int wm = wv >> 2;      // 0..1
    const int wn = wv & 3;       // 0..3
    const int l15 = lane & 15, lhi = lane >> 4;
    const int key = l15 & 7;
    const int lr8 = lane >> 3;                 // 0..7
    const int sl  = (lane & 7) ^ lr8;          // pre-swizzled global k-slot

    // staging source byte-offsets (u32; max buffer 268 MB)
    uint32_t aOff[2][2], bOff[2][2];
    #pragma unroll
    for (int mh = 0; mh < 2; ++mh)
        #pragma unroll
        for (int c = 0; c < 2; ++c) {
            int tr = mh * 64 + wv * 8 + lr8 + c * 128;
            int gr = row0 + tr; if (gr > TOTROW - 1) gr = TOTROW - 1;
            uint32_t rowid = GATHER ? (uint32_t)rowinfo[gr] : (uint32_t)gr;
            aOff[mh][c] = rowid * (uint32_t)(K * 2) + sl * 16;
        }
    #pragma unroll
    for (int nh = 0; nh < 2; ++nh)
        #pragma unroll
        for (int c = 0; c < 2; ++c) {
            int tr = (wv >> 2) * 64 + nh * 32 + (wv & 3) * 8 + lr8 + c * 128;
            bOff[nh][c] = ((uint32_t)e * Ncols + col0 + tr) * (uint32_t)(K * 2) + sl * 16;
        }

    const int arb = wv * 8;                               // A LDS row base (+mh*64, +128 for c=1)
    const int brb = (wv >> 2) * 64 + (wv & 3) * 8;        // B LDS row base (+nh*32, +128 for c=1)

    auto stageA = [&](int buf, int mh, int kt) {
        gload_lds16((const char*)Ah + aOff[mh][0] + kt * 128, (void*)&As[buf][mh * 64 + arb][0]);
        gload_lds16((const char*)Ah + aOff[mh][1] + kt * 128, (void*)&As[buf][128 + mh * 64 + arb][0]);
    };
    auto stageB = [&](int buf, int nh, int kt) {
        gload_lds16((const char*)BT + bOff[nh][0] + kt * 128, (void*)&Bs[buf][nh * 32 + brb][0]);
        gload_lds16((const char*)BT + bOff[nh][1] + kt * 128, (void*)&Bs[buf][128 + nh * 32 + brb][0]);
    };

    f32x4 acc[8][4];
    #pragma unroll
    for (int i = 0; i < 8; ++i)
        #pragma unroll
        for (int j = 0; j < 4; ++j)
            acc[i][j] = (f32x4){0.f, 0.f, 0.f, 0.f};

    short8 aregA[4][2], aregB[4][2], breg0[2][2], bregN1[2][2];

    const int KT = K / 64;
    const int NIT = KT / 2;

    // prologue: buf0 kt0 fully; buf1 kt1 units A-mh0, B-nh1 (the "prev-ph7/ph8" units)
    stageA(0, 0, 0); stageA(0, 1, 0); stageB(0, 0, 0); stageB(0, 1, 0);
    stageA(1, 0, 1); stageB(1, 1, 1);
    asm volatile("s_waitcnt vmcnt(4)" ::: "memory");   // buf0 landed (own loads)
    SBAR;                                              // publish across waves
    RD_A(aregA, 0, 0); RD_B(breg0, 0, 0);              // regs for ph1
    SCH0;

    for (int i2 = 0; i2 < NIT - 1; ++i2) {
        const int kt1 = 2 * i2 + 1, kt2 = 2 * i2 + 2, kt3 = 2 * i2 + 3;
        /*ph1*/ RD_B(bregN1, 0, 1);                   stageA(1, 1, kt1); SCH0; SBAR; MM(aregA, breg0,  0, 0);      SBAR;
        /*ph2*/ RD_A(aregB, 0, 1);                    stageB(1, 0, kt1); SCH0; SBAR; MM(aregA, bregN1, 0, 1);      SBAR;
        /*ph3*/                                       stageA(0, 0, kt2); SCH0; SBAR; MM(aregB, breg0,  1, 0); VW2; SBAR;
        /*ph4*/ RD_A(aregA, 1, 0); RD_B(breg0, 1, 0); stageB(0, 1, kt2); SCH0; SBAR; MM(aregB, bregN1, 1, 1);      SBAR;
        /*ph5*/ RD_B(bregN1, 1, 1);                   stageA(0, 1, kt2); SCH0; SBAR; MM(aregA, breg0,  0, 0);      SBAR;
        /*ph6*/ RD_A(aregB, 1, 1);                    stageB(0, 0, kt2); SCH0; SBAR; MM(aregA, bregN1, 0, 1);      SBAR;
        /*ph7*/                                       stageA(1, 0, kt3); SCH0; SBAR; MM(aregB, breg0,  1, 0); VW2; SBAR;
        /*ph8*/ RD_A(aregA, 0, 0); RD_B(breg0, 0, 0); stageB(1, 1, kt3); SCH0; SBAR; MM(aregB, bregN1, 1, 1);      SBAR;
    }
    {   // final iteration: no kt2/kt3 staging; full drain at ph3-tail
        const int kt1 = 2 * (NIT - 1) + 1;
        /*f1*/ RD_B(bregN1, 0, 1);                   stageA(1, 1, kt1); SCH0; SBAR; MM(aregA, breg0,  0, 0);      SBAR;
        /*f2*/ RD_A(aregB, 0, 1);                    stageB(1, 0, kt1); SCH0; SBAR; MM(aregA, bregN1, 0, 1);      SBAR;
        /*f3*/                                                                SBAR; MM(aregB, breg0,  1, 0); VW0; SBAR;
        /*f4*/ RD_A(aregA, 1, 0); RD_B(breg0, 1, 0);                    SCH0; SBAR; MM(aregB, bregN1, 1, 1);      SBAR;
        /*f5*/ RD_B(bregN1, 1, 1);                                      SCH0; SBAR; MM(aregA, breg0,  0, 0);      SBAR;
        /*f6*/ RD_A(aregB, 1, 1);                                       SCH0; SBAR; MM(aregA, bregN1, 0, 1);      SBAR;
        /*f7*/                                                                SBAR; MM(aregB, breg0,  1, 0);      SBAR;
        /*f8*/                                                                      MM(aregB, bregN1, 1, 1);
    }

    // epilogue: C/D layout col=lane&15, row=(lane>>4)*4+q
    #pragma unroll
    for (int n = 0; n < 4; ++n) {
        int colg = col0 + wn * 64 + n * 16 + l15;
        float bv = bias[e * Ncols + colg];
        #pragma unroll
        for (int m = 0; m < 8; ++m) {
            #pragma unroll
            for (int q = 0; q < 4; ++q) {
                int rl = mt * 256 + wm * 128 + m * 16 + lhi * 4 + q;
                if (rl < cnte) {
                    float v = acc[m][n][q] + bv;
                    if (GELU_ACT) v = gelu_f(v);
                    C[(size_t)(base_e + rl) * Ncols + colg] = f2bf(v);
                }
            }
        }
    }
}

// ---------------- combine: out[n] = 0.5*(Y[r1] + Y[r2]) ----------------
__global__ __launch_bounds__(256) void combine_kernel(
    const ushort_t* __restrict__ Y, const int* __restrict__ token_rows,
    float* __restrict__ out)
{
    int n = blockIdx.x;
    int t = threadIdx.x;
    int r1 = token_rows[n * 2 + 0], r2 = token_rows[n * 2 + 1];
    const ushort_t* y1 = Y + (size_t)r1 * D_MODEL + t * 4;
    const ushort_t* y2 = Y + (size_t)r2 * D_MODEL + t * 4;
    ushort_t a[4], b[4];
    *(uint2*)a = *(const uint2*)y1;
    *(uint2*)b = *(const uint2*)y2;
    float4 o;
    o.x = 0.5f * (bf2f(a[0]) + bf2f(b[0]));
    o.y = 0.5f * (bf2f(a[1]) + bf2f(b[1]));
    o.z = 0.5f * (bf2f(a[2]) + bf2f(b[2]));
    o.w = 0.5f * (bf2f(a[3]) + bf2f(b[3]));
    *(float4*)(out + (size_t)n * D_MODEL + t * 4) = o;
}

extern "C" void kernel_launch(void* const* d_in, const int* in_sizes, int n_in,
                              void* d_out, int out_size, void* d_ws, size_t ws_size,
                              hipStream_t stream)
{
    const float* x  = (const float*)d_in[0];
    const float* et = (const float*)d_in[1];
    const float* W1 = (const float*)d_in[2];
    const float* b1 = (const float*)d_in[3];
    const float* W2 = (const float*)d_in[4];
    const float* b2 = (const float*)d_in[5];
    const float* W3 = (const float*)d_in[6];
    const float* b3 = (const float*)d_in[7];
    float* out = (float*)d_out;

    char* ws = (char*)d_ws;
    size_t off = 0;
    auto alloc = [&](size_t bytes) -> char* {
        char* p = ws + off;
        off += (bytes + 255) & ~(size_t)255;
        return p;
    };
    int* cnt        = (int*)alloc(NEXP * 4);
    int* basep      = (int*)alloc(NEXP * 4);
    int* cnt2       = (int*)alloc(NEXP * 4);
    int* top2       = (int*)alloc((size_t)NTOK * 2 * 4);
    int* token_rows = (int*)alloc((size_t)NTOK * 2 * 4);
    int* rowinfo    = (int*)alloc((size_t)TOTROW * 4);
    ushort_t* W1T = (ushort_t*)alloc((size_t)NEXP * D_HID * D_MODEL * 2);
    ushort_t* W2T = (ushort_t*)alloc((size_t)NEXP * D_HID * D_HID * 2);
    ushort_t* W3T = (ushort_t*)alloc((size_t)NEXP * D_MODEL * D_HID * 2);
    ushort_t* H1  = (ushort_t*)alloc((size_t)TOTROW * D_HID * 2);
    ushort_t* H2  = (ushort_t*)alloc((size_t)TOTROW * D_HID * 2);
    ushort_t* Yr  = (ushort_t*)alloc((size_t)TOTROW * D_MODEL * 2);
    if (off > ws_size) return; // workspace too small: fail loudly (wrong output)

    // xb (bf16 x) aliases H2: dead until GEMM2 writes H2.
    ushort_t* xb = H2;

    hipMemsetAsync(cnt, 0, NEXP * 4, stream);
    router_kernel<<<NTOK / 4, 256, 0, stream>>>(x, et, cnt, top2);
    scan_kernel<<<1, 64, 0, stream>>>(cnt, basep, cnt2);
    assign_kernel<<<NTOK / 256, 256, 0, stream>>>(top2, basep, cnt2, rowinfo, token_rows);

    convert_x<<<(NTOK * D_MODEL) / 1024, 256, 0, stream>>>(x, xb);

    transpose_kernel<<<dim3(D_HID / 64, D_MODEL / 64, NEXP), 256, 0, stream>>>(W1, W1T, D_MODEL, D_HID);
    transpose_kernel<<<dim3(D_HID / 64, D_HID / 64, NEXP), 256, 0, stream>>>(W2, W2T, D_HID, D_HID);
    transpose_kernel<<<dim3(D_MODEL / 64, D_HID / 64, NEXP), 256, 0, stream>>>(W3, W3T, D_HID, D_MODEL);

    moe_gemm8<true, true><<<dim3(D_HID / 256, 16, NEXP), 512, 0, stream>>>(
        xb, W1T, b1, H1, cnt, basep, rowinfo, D_HID, D_MODEL);
    moe_gemm8<false, true><<<dim3(D_HID / 256, 16, NEXP), 512, 0, stream>>>(
        H1, W2T, b2, H2, cnt, basep, rowinfo, D_HID, D_HID);
    moe_gemm8<false, false><<<dim3(D_MODEL / 256, 16, NEXP), 512, 0, stream>>>(
        H2, W3T, b3, Yr, cnt, basep, rowinfo, D_MODEL, D_HID);

    combine_kernel<<<NTOK, 256, 0, stream>>>(Yr, token_rows, out);
}

// Round 6
// 1589.201 us; speedup vs baseline: 1.8864x; 1.8822x over previous
//
#include <hip/hip_runtime.h>
#include <stdint.h>

#define D_MODEL 1024
#define D_HID   4096
#define NEXP    8
#define NTOK    8192
#define TOTROW  (NTOK*2)

typedef unsigned short ushort_t;
typedef __attribute__((ext_vector_type(8))) short short8;
typedef __attribute__((ext_vector_type(4))) float f32x4;

static __device__ __forceinline__ ushort_t f2bf(float f) {
    union { float f; uint32_t u; } v; v.f = f;
    uint32_t u = v.u;
    uint32_t r = (u + 0x7FFFu + ((u >> 16) & 1u)) >> 16;
    return (ushort_t)r;
}
static __device__ __forceinline__ float bf2f(ushort_t h) {
    union { uint32_t u; float f; } v; v.u = ((uint32_t)h) << 16;
    return v.f;
}
static __device__ __forceinline__ float gelu_f(float x) {
    return 0.5f * x * (1.0f + erff(x * 0.70710678118654752f));
}

static __device__ __forceinline__ void gload_lds16(const void* g, void* l) {
    __builtin_amdgcn_global_load_lds(
        (const __attribute__((address_space(1))) void*)g,
        (__attribute__((address_space(3))) void*)l,
        16, 0, 0);
}

// ---------------- router ----------------
__global__ __launch_bounds__(256) void router_kernel(
    const float* __restrict__ x, const float* __restrict__ et,
    int* __restrict__ cnt, int* __restrict__ top2)
{
    __shared__ float lds_et[NEXP * D_MODEL];
    int t = threadIdx.x;
    #pragma unroll
    for (int i = 0; i < (NEXP * D_MODEL) / 256; ++i)
        lds_et[i * 256 + t] = et[i * 256 + t];
    __syncthreads();

    int lane = t & 63, wv = t >> 6;
    int n = blockIdx.x * 4 + wv;
    double s[NEXP];
    #pragma unroll
    for (int e = 0; e < NEXP; ++e) s[e] = 0.0;
    const float* xr = x + (size_t)n * D_MODEL;
    for (int it = 0; it < D_MODEL / 64; ++it) {
        float xv = xr[it * 64 + lane];
        #pragma unroll
        for (int e = 0; e < NEXP; ++e)
            s[e] += (double)(xv * lds_et[e * D_MODEL + it * 64 + lane]);
    }
    #pragma unroll
    for (int e = 0; e < NEXP; ++e)
        for (int off = 32; off; off >>= 1)
            s[e] += __shfl_xor(s[e], off);

    if (lane == 0) {
        int e1 = 0;
        for (int e = 1; e < NEXP; ++e) if (s[e] > s[e1]) e1 = e;
        int e2 = (e1 == 0) ? 1 : 0;
        for (int e = 0; e < NEXP; ++e) if (e != e1 && s[e] > s[e2]) e2 = e;
        top2[n * 2 + 0] = e1;
        top2[n * 2 + 1] = e2;
        atomicAdd(&cnt[e1], 1);
        atomicAdd(&cnt[e2], 1);
    }
}

__global__ void scan_kernel(const int* __restrict__ cnt, int* __restrict__ base,
                            int* __restrict__ cnt2)
{
    if (threadIdx.x == 0 && blockIdx.x == 0) {
        int acc = 0;
        for (int e = 0; e < NEXP; ++e) { base[e] = acc; acc += cnt[e]; cnt2[e] = 0; }
    }
}

__global__ __launch_bounds__(256) void assign_kernel(
    const int* __restrict__ top2, const int* __restrict__ base,
    int* __restrict__ cnt2, int* __restrict__ rowinfo, int* __restrict__ token_rows)
{
    int n = blockIdx.x * 256 + threadIdx.x;
    if (n >= NTOK) return;
    #pragma unroll
    for (int k = 0; k < 2; ++k) {
        int e = top2[n * 2 + k];
        int slot = atomicAdd(&cnt2[e], 1);
        int row = base[e] + slot;
        rowinfo[row] = n;
        token_rows[n * 2 + k] = row;
    }
}

// ---------------- x fp32 -> bf16 ----------------
__global__ __launch_bounds__(256) void convert_x(
    const float* __restrict__ x, ushort_t* __restrict__ xb)
{
    size_t i = ((size_t)blockIdx.x * 256 + threadIdx.x) * 4;
    float4 f = *(const float4*)(x + i);
    ushort_t o[4];
    o[0] = f2bf(f.x); o[1] = f2bf(f.y); o[2] = f2bf(f.z); o[3] = f2bf(f.w);
    *(uint2*)(xb + i) = *(const uint2*)o;
}

// ------------- weight transpose+convert: [E][K][N] f32 -> [E][N][K] bf16 -------------
__global__ __launch_bounds__(256) void transpose_kernel(
    const float* __restrict__ in, ushort_t* __restrict__ out, int K, int N)
{
    __shared__ float tile[64][65];
    int e = blockIdx.z;
    int k0 = blockIdx.y * 64, n0 = blockIdx.x * 64;
    const float* ine = in + (size_t)e * K * N + (size_t)k0 * N + n0;
    ushort_t* oute = out + (size_t)e * N * K + (size_t)n0 * K + k0;
    int t = threadIdx.x;
    int lr = t >> 4;
    int lc = (t & 15) * 4;
    #pragma unroll
    for (int i = 0; i < 4; ++i) {
        float4 v = *(const float4*)(ine + (size_t)(i * 16 + lr) * N + lc);
        tile[i * 16 + lr][lc + 0] = v.x;
        tile[i * 16 + lr][lc + 1] = v.y;
        tile[i * 16 + lr][lc + 2] = v.z;
        tile[i * 16 + lr][lc + 3] = v.w;
    }
    __syncthreads();
    int nr = t >> 3;
    int kg = (t & 7) * 8;
    #pragma unroll
    for (int j = 0; j < 2; ++j) {
        int n = j * 32 + nr;
        ushort_t o[8];
        #pragma unroll
        for (int m = 0; m < 8; ++m) o[m] = f2bf(tile[kg + m][n]);
        *(uint4*)(oute + (size_t)n * K + kg) = *(const uint4*)o;
    }
}

// ================= grouped GEMM: 256x256 tile, BK=64, 8-phase (m201 skeleton) =================
// LDS[side][buf][row][slot]: slot s holds global k-slot s^(row&7) (source pre-swizzle,
// linear gload_lds dest). Same-phase register reads: ds_read -> barrier -> lgkmcnt(0) ->
// MFMA -> barrier (m201 template). vmcnt(4) at ph4/ph8 only; vmcnt(0) in final iter.
// All ds_read addresses = precomputed per-thread base pointer + compile-time constant
// (folds into ds_read offset: immediate -> ~zero per-phase VALU).
// Epilogue: acc -> chunk-XOR-swizzled LDS C-tile -> coalesced 64B-contiguous dwordx4 stores
// (kills the 2x partial-sector write amplification of scalar 2B stores).

#define RD_A(BUF, MH) do {                                                        \
    _Pragma("unroll") for (int mi = 0; mi < 4; ++mi) {                            \
        areg[mi][0] = *(const short8*)(pA0 + (BUF)*16384 + (MH)*4096 + mi*1024);  \
        areg[mi][1] = *(const short8*)(pA1 + (BUF)*16384 + (MH)*4096 + mi*1024);  \
    }                                                                             \
} while (0)

#define RD_B(DST, BUF, NH) do {                                                   \
    _Pragma("unroll") for (int ni = 0; ni < 2; ++ni) {                            \
        DST[ni][0] = *(const short8*)(pB0 + (BUF)*16384 + (NH)*2048 + ni*1024);   \
        DST[ni][1] = *(const short8*)(pB1 + (BUF)*16384 + (NH)*2048 + ni*1024);   \
    }                                                                             \
} while (0)

#define PHASE(BUF, MH, NH, LA, LB, BREG, STAGE_STMT, TAIL_STMT)                   \
  do {                                                                            \
    if (LA) RD_A(BUF, MH);                                                        \
    if (LB) RD_B(BREG, BUF, NH);                                                  \
    STAGE_STMT;                                                                   \
    __builtin_amdgcn_s_barrier();                                                 \
    asm volatile("s_waitcnt lgkmcnt(0)" ::: "memory");                            \
    __builtin_amdgcn_s_setprio(1);                                                \
    _Pragma("unroll") for (int mi = 0; mi < 4; ++mi)                              \
    _Pragma("unroll") for (int ni = 0; ni < 2; ++ni)                              \
    _Pragma("unroll") for (int ks = 0; ks < 2; ++ks)                              \
      acc[(MH)*4 + mi][(NH)*2 + ni] = __builtin_amdgcn_mfma_f32_16x16x32_bf16(    \
          areg[mi][ks], BREG[ni][ks], acc[(MH)*4 + mi][(NH)*2 + ni], 0, 0, 0);    \
    __builtin_amdgcn_s_setprio(0);                                                \
    TAIL_STMT;                                                                    \
    __builtin_amdgcn_s_barrier();                                                 \
  } while (0)

#define VW4 asm volatile("s_waitcnt vmcnt(4)" ::: "memory")
#define VW0 asm volatile("s_waitcnt vmcnt(0)" ::: "memory")
#define VNO ((void)0)

template<bool GATHER, bool GELU_ACT>
__global__ __launch_bounds__(512, 2) void moe_gemm8(
    const ushort_t* __restrict__ Ah,
    const ushort_t* __restrict__ BT,
    const float* __restrict__ bias,
    ushort_t* __restrict__ C,
    const int* __restrict__ cnt, const int* __restrict__ basep,
    const int* __restrict__ rowinfo,
    int Ncols, int K)
{
    const int e = blockIdx.z;
    const int cnte = cnt[e];
    const int mt = blockIdx.y;
    if (mt * 256 >= cnte) return;
    const int base_e = basep[e];
    const int row0 = base_e + mt * 256;
    const int col0 = blockIdx.x * 256;

    // SMEM[0] = A tiles (2 bufs), SMEM[1] = B tiles; reused as C-tile in epilogue.
    __shared__ __attribute__((aligned(16))) ushort_t SMEM[2][2][256][64]; // 128 KB

    const int t = threadIdx.x;
    const int lane = t & 63;
    const int wv = t >> 6;       // 0..7
    const int wm = wv >> 2;      // 0..1
    const int wn = wv & 3;       // 0..3
    const int l15 = lane & 15, lhi = lane >> 4;
    const int key = l15 & 7;
    const int lr8 = lane >> 3;                 // 0..7
    const int sl  = (lane & 7) ^ lr8;          // pre-swizzled global k-slot

    // per-thread LDS fragment base pointers (all reads = base + const, folds to offset:)
    const int slot0 = (lhi ^ key) * 8;         // ks=0
    const int slot1 = ((4 + lhi) ^ key) * 8;   // ks=1
    const ushort_t* pA0 = &SMEM[0][0][wm * 128 + l15][slot0];
    const ushort_t* pA1 = &SMEM[0][0][wm * 128 + l15][slot1];
    const ushort_t* pB0 = &SMEM[1][0][wn * 64 + l15][slot0];
    const ushort_t* pB1 = &SMEM[1][0][wn * 64 + l15][slot1];

    // running global byte offsets (advance +128B per stage of that unit)
    uint32_t aOff[2][2], bOff[2][2];
    #pragma unroll
    for (int mh = 0; mh < 2; ++mh)
        #pragma unroll
        for (int c = 0; c < 2; ++c) {
            int tr = mh * 64 + wv * 8 + lr8 + c * 128;
            int gr = row0 + tr; if (gr > TOTROW - 1) gr = TOTROW - 1;
            uint32_t rowid = GATHER ? (uint32_t)rowinfo[gr] : (uint32_t)gr;
            aOff[mh][c] = rowid * (uint32_t)(K * 2) + sl * 16;
        }
    #pragma unroll
    for (int nh = 0; nh < 2; ++nh)
        #pragma unroll
        for (int c = 0; c < 2; ++c) {
            int tr = (wv >> 2) * 64 + nh * 32 + (wv & 3) * 8 + lr8 + c * 128;
            bOff[nh][c] = ((uint32_t)e * Ncols + col0 + tr) * (uint32_t)(K * 2) + sl * 16;
        }

    const int arb = wv * 8;
    const int brb = (wv >> 2) * 64 + (wv & 3) * 8;

    auto stageA = [&](int buf, int mh) {
        gload_lds16((const char*)Ah + aOff[mh][0], (void*)&SMEM[0][buf][mh * 64 + arb][0]);
        gload_lds16((const char*)Ah + aOff[mh][1], (void*)&SMEM[0][buf][128 + mh * 64 + arb][0]);
        aOff[mh][0] += 128; aOff[mh][1] += 128;
    };
    auto stageB = [&](int buf, int nh) {
        gload_lds16((const char*)BT + bOff[nh][0], (void*)&SMEM[1][buf][nh * 32 + brb][0]);
        gload_lds16((const char*)BT + bOff[nh][1], (void*)&SMEM[1][buf][128 + nh * 32 + brb][0]);
        bOff[nh][0] += 128; bOff[nh][1] += 128;
    };

    f32x4 acc[8][4];
    #pragma unroll
    for (int i = 0; i < 8; ++i)
        #pragma unroll
        for (int j = 0; j < 4; ++j)
            acc[i][j] = (f32x4){0.f, 0.f, 0.f, 0.f};

    short8 areg[4][2], breg0[2][2], breg1[2][2];

    const int KT = K / 64;
    const int NIT = KT / 2;

    // prologue: buf0 fully (kt0) + buf1 early units (kt1)
    stageA(0, 0); stageA(0, 1); stageB(0, 0); stageB(0, 1);
    stageA(1, 0); stageB(1, 1);
    VW4;   // buf0's 8 loads landed (buf1's 4 may fly)
    __builtin_amdgcn_s_barrier();

    for (int i2 = 0; i2 < NIT - 1; ++i2) {
        /*ph1*/ PHASE(0, 0, 0, true,  true,  breg0, stageA(1, 1), VNO);
        /*ph2*/ PHASE(0, 0, 1, false, true,  breg1, stageB(1, 0), VNO);
        /*ph3*/ PHASE(0, 1, 1, true,  false, breg1, stageA(0, 0), VNO);
        /*ph4*/ PHASE(0, 1, 0, false, false, breg0, stageB(0, 1), VW4);
        /*ph5*/ PHASE(1, 0, 0, true,  true,  breg0, stageA(0, 1), VNO);
        /*ph6*/ PHASE(1, 0, 1, false, true,  breg1, stageB(0, 0), VNO);
        /*ph7*/ PHASE(1, 1, 1, true,  false, breg1, stageA(1, 0), VNO);
        /*ph8*/ PHASE(1, 1, 0, false, false, breg0, stageB(1, 1), VW4);
    }
    {   // final iteration: stage only buf1's remaining kt1 units; drain at ph4
        /*f1*/ PHASE(0, 0, 0, true,  true,  breg0, stageA(1, 1), VNO);
        /*f2*/ PHASE(0, 0, 1, false, true,  breg1, stageB(1, 0), VNO);
        /*f3*/ PHASE(0, 1, 1, true,  false, breg1, VNO,          VNO);
        /*f4*/ PHASE(0, 1, 0, false, false, breg0, VNO,          VW0);
        /*f5*/ PHASE(1, 0, 0, true,  true,  breg0, VNO,          VNO);
        /*f6*/ PHASE(1, 0, 1, false, true,  breg1, VNO,          VNO);
        /*f7*/ PHASE(1, 1, 1, true,  false, breg1, VNO,          VNO);
        /*f8: no trailing barrier needed — epilogue syncs below */
        asm volatile("s_waitcnt lgkmcnt(0)" ::: "memory");
        #pragma unroll
        for (int mi = 0; mi < 4; ++mi)
            #pragma unroll
            for (int ni = 0; ni < 2; ++ni)
                #pragma unroll
                for (int ks = 0; ks < 2; ++ks)
                    acc[4 + mi][ni] = __builtin_amdgcn_mfma_f32_16x16x32_bf16(
                        areg[mi][ks], breg0[ni][ks], acc[4 + mi][ni], 0, 0, 0);
    }

    // ---- epilogue: acc -> swizzled LDS C-tile -> coalesced stores ----
    // C-tile: 256 rows x 256 cols bf16 over the full 128KB SMEM.
    // elem(r, c) = r*256 + ((c>>3) ^ ((r&7)<<2))*8 + (c&7)   (16B-chunk XOR swizzle)
    ushort_t* ctile = &SMEM[0][0][0][0];
    #pragma unroll
    for (int n = 0; n < 4; ++n) {
        int c = wn * 64 + n * 16 + l15;
        float bv = bias[e * Ncols + col0 + c];
        #pragma unroll
        for (int m = 0; m < 8; ++m) {
            #pragma unroll
            for (int q = 0; q < 4; ++q) {
                int r = wm * 128 + m * 16 + lhi * 4 + q;
                float v = acc[m][n][q] + bv;
                if (GELU_ACT) v = gelu_f(v);
                ctile[r * 256 + ((c >> 3) ^ ((r & 7) << 2)) * 8 + (c & 7)] = f2bf(v);
            }
        }
    }
    __syncthreads();
    {
        int rr = t >> 2;          // 0..127
        int ch0 = t & 3;
        #pragma unroll
        for (int pass = 0; pass < 2; ++pass) {
            int r = pass * 128 + rr;
            int rl = mt * 256 + r;
            if (rl < cnte) {
                size_t gbase = (size_t)(base_e + rl) * Ncols + col0;
                #pragma unroll
                for (int i = 0; i < 8; ++i) {
                    int ch = ch0 + i * 4;
                    uint4 v = *(const uint4*)&ctile[r * 256 + ((ch ^ ((r & 7) << 2)) * 8)];
                    *(uint4*)&C[gbase + ch * 8] = v;
                }
            }
        }
    }
}

// ---------------- combine: out[n] = 0.5*(Y[r1] + Y[r2]) ----------------
__global__ __launch_bounds__(256) void combine_kernel(
    const ushort_t* __restrict__ Y, const int* __restrict__ token_rows,
    float* __restrict__ out)
{
    int n = blockIdx.x;
    int t = threadIdx.x;
    int r1 = token_rows[n * 2 + 0], r2 = token_rows[n * 2 + 1];
    const ushort_t* y1 = Y + (size_t)r1 * D_MODEL + t * 4;
    const ushort_t* y2 = Y + (size_t)r2 * D_MODEL + t * 4;
    ushort_t a[4], b[4];
    *(uint2*)a = *(const uint2*)y1;
    *(uint2*)b = *(const uint2*)y2;
    float4 o;
    o.x = 0.5f * (bf2f(a[0]) + bf2f(b[0]));
    o.y = 0.5f * (bf2f(a[1]) + bf2f(b[1]));
    o.z = 0.5f * (bf2f(a[2]) + bf2f(b[2]));
    o.w = 0.5f * (bf2f(a[3]) + bf2f(b[3]));
    *(float4*)(out + (size_t)n * D_MODEL + t * 4) = o;
}

extern "C" void kernel_launch(void* const* d_in, const int* in_sizes, int n_in,
                              void* d_out, int out_size, void* d_ws, size_t ws_size,
                              hipStream_t stream)
{
    const float* x  = (const float*)d_in[0];
    const float* et = (const float*)d_in[1];
    const float* W1 = (const float*)d_in[2];
    const float* b1 = (const float*)d_in[3];
    const float* W2 = (const float*)d_in[4];
    const float* b2 = (const float*)d_in[5];
    const float* W3 = (const float*)d_in[6];
    const float* b3 = (const float*)d_in[7];
    float* out = (float*)d_out;

    char* ws = (char*)d_ws;
    size_t off = 0;
    auto alloc = [&](size_t bytes) -> char* {
        char* p = ws + off;
        off += (bytes + 255) & ~(size_t)255;
        return p;
    };
    int* cnt        = (int*)alloc(NEXP * 4);
    int* basep      = (int*)alloc(NEXP * 4);
    int* cnt2       = (int*)alloc(NEXP * 4);
    int* top2       = (int*)alloc((size_t)NTOK * 2 * 4);
    int* token_rows = (int*)alloc((size_t)NTOK * 2 * 4);
    int* rowinfo    = (int*)alloc((size_t)TOTROW * 4);
    ushort_t* W1T = (ushort_t*)alloc((size_t)NEXP * D_HID * D_MODEL * 2);
    ushort_t* W2T = (ushort_t*)alloc((size_t)NEXP * D_HID * D_HID * 2);
    ushort_t* W3T = (ushort_t*)alloc((size_t)NEXP * D_MODEL * D_HID * 2);
    ushort_t* H1  = (ushort_t*)alloc((size_t)TOTROW * D_HID * 2);
    ushort_t* H2  = (ushort_t*)alloc((size_t)TOTROW * D_HID * 2);
    ushort_t* Yr  = (ushort_t*)alloc((size_t)TOTROW * D_MODEL * 2);
    if (off > ws_size) return; // workspace too small: fail loudly (wrong output)

    // xb (bf16 x) aliases H2: dead until GEMM2 writes H2.
    ushort_t* xb = H2;

    hipMemsetAsync(cnt, 0, NEXP * 4, stream);
    router_kernel<<<NTOK / 4, 256, 0, stream>>>(x, et, cnt, top2);
    scan_kernel<<<1, 64, 0, stream>>>(cnt, basep, cnt2);
    assign_kernel<<<NTOK / 256, 256, 0, stream>>>(top2, basep, cnt2, rowinfo, token_rows);

    convert_x<<<(NTOK * D_MODEL) / 1024, 256, 0, stream>>>(x, xb);

    transpose_kernel<<<dim3(D_HID / 64, D_MODEL / 64, NEXP), 256, 0, stream>>>(W1, W1T, D_MODEL, D_HID);
    transpose_kernel<<<dim3(D_HID / 64, D_HID / 64, NEXP), 256, 0, stream>>>(W2, W2T, D_HID, D_HID);
    transpose_kernel<<<dim3(D_MODEL / 64, D_HID / 64, NEXP), 256, 0, stream>>>(W3, W3T, D_HID, D_MODEL);

    moe_gemm8<true, true><<<dim3(D_HID / 256, 16, NEXP), 512, 0, stream>>>(
        xb, W1T, b1, H1, cnt, basep, rowinfo, D_HID, D_MODEL);
    moe_gemm8<false, true><<<dim3(D_HID / 256, 16, NEXP), 512, 0, stream>>>(
        H1, W2T, b2, H2, cnt, basep, rowinfo, D_HID, D_HID);
    moe_gemm8<false, false><<<dim3(D_MODEL / 256, 16, NEXP), 512, 0, stream>>>(
        H2, W3T, b3, Yr, cnt, basep, rowinfo, D_MODEL, D_HID);

    combine_kernel<<<NTOK, 256, 0, stream>>>(Yr, token_rows, out);
}

// Round 8
// 1501.585 us; speedup vs baseline: 1.9965x; 1.0583x over previous
//
#include <hip/hip_runtime.h>
#include <stdint.h>

#define D_MODEL 1024
#define D_HID   4096
#define NEXP    8
#define NTOK    8192
#define TOTROW  (NTOK*2)

typedef unsigned short ushort_t;
typedef __attribute__((ext_vector_type(8))) short short8;
typedef __attribute__((ext_vector_type(4))) float f32x4;

static __device__ __forceinline__ ushort_t f2bf(float f) {
    union { float f; uint32_t u; } v; v.f = f;
    uint32_t u = v.u;
    uint32_t r = (u + 0x7FFFu + ((u >> 16) & 1u)) >> 16;
    return (ushort_t)r;
}
static __device__ __forceinline__ float bf2f(ushort_t h) {
    union { uint32_t u; float f; } v; v.u = ((uint32_t)h) << 16;
    return v.f;
}
static __device__ __forceinline__ float gelu_f(float x) {
    return 0.5f * x * (1.0f + erff(x * 0.70710678118654752f));
}

static __device__ __forceinline__ void gload_lds16(const void* g, void* l) {
    __builtin_amdgcn_global_load_lds(
        (const __attribute__((address_space(1))) void*)g,
        (__attribute__((address_space(3))) void*)l,
        16, 0, 0);
}

// ---------------- router ----------------
__global__ __launch_bounds__(256) void router_kernel(
    const float* __restrict__ x, const float* __restrict__ et,
    int* __restrict__ cnt, int* __restrict__ top2)
{
    __shared__ float lds_et[NEXP * D_MODEL];
    int t = threadIdx.x;
    #pragma unroll
    for (int i = 0; i < (NEXP * D_MODEL) / 256; ++i)
        lds_et[i * 256 + t] = et[i * 256 + t];
    __syncthreads();

    int lane = t & 63, wv = t >> 6;
    int n = blockIdx.x * 4 + wv;
    double s[NEXP];
    #pragma unroll
    for (int e = 0; e < NEXP; ++e) s[e] = 0.0;
    const float* xr = x + (size_t)n * D_MODEL;
    for (int it = 0; it < D_MODEL / 64; ++it) {
        float xv = xr[it * 64 + lane];
        #pragma unroll
        for (int e = 0; e < NEXP; ++e)
            s[e] += (double)(xv * lds_et[e * D_MODEL + it * 64 + lane]);
    }
    #pragma unroll
    for (int e = 0; e < NEXP; ++e)
        for (int off = 32; off; off >>= 1)
            s[e] += __shfl_xor(s[e], off);

    if (lane == 0) {
        int e1 = 0;
        for (int e = 1; e < NEXP; ++e) if (s[e] > s[e1]) e1 = e;
        int e2 = (e1 == 0) ? 1 : 0;
        for (int e = 0; e < NEXP; ++e) if (e != e1 && s[e] > s[e2]) e2 = e;
        top2[n * 2 + 0] = e1;
        top2[n * 2 + 1] = e2;
        atomicAdd(&cnt[e1], 1);
        atomicAdd(&cnt[e2], 1);
    }
}

__global__ void scan_kernel(const int* __restrict__ cnt, int* __restrict__ base,
                            int* __restrict__ cnt2)
{
    if (threadIdx.x == 0 && blockIdx.x == 0) {
        int acc = 0;
        for (int e = 0; e < NEXP; ++e) { base[e] = acc; acc += cnt[e]; cnt2[e] = 0; }
    }
}

__global__ __launch_bounds__(256) void assign_kernel(
    const int* __restrict__ top2, const int* __restrict__ base,
    int* __restrict__ cnt2, int* __restrict__ rowinfo, int* __restrict__ token_rows)
{
    int n = blockIdx.x * 256 + threadIdx.x;
    if (n >= NTOK) return;
    #pragma unroll
    for (int k = 0; k < 2; ++k) {
        int e = top2[n * 2 + k];
        int slot = atomicAdd(&cnt2[e], 1);
        int row = base[e] + slot;
        rowinfo[row] = n;
        token_rows[n * 2 + k] = row;
    }
}

// ---------------- x fp32 -> bf16 ----------------
__global__ __launch_bounds__(256) void convert_x(
    const float* __restrict__ x, ushort_t* __restrict__ xb)
{
    size_t i = ((size_t)blockIdx.x * 256 + threadIdx.x) * 4;
    float4 f = *(const float4*)(x + i);
    ushort_t o[4];
    o[0] = f2bf(f.x); o[1] = f2bf(f.y); o[2] = f2bf(f.z); o[3] = f2bf(f.w);
    *(uint2*)(xb + i) = *(const uint2*)o;
}

// ------------- weight transpose+convert: [E][K][N] f32 -> [E][N][K] bf16 -------------
__global__ __launch_bounds__(256) void transpose_kernel(
    const float* __restrict__ in, ushort_t* __restrict__ out, int K, int N)
{
    __shared__ float tile[64][65];
    int e = blockIdx.z;
    int k0 = blockIdx.y * 64, n0 = blockIdx.x * 64;
    const float* ine = in + (size_t)e * K * N + (size_t)k0 * N + n0;
    ushort_t* oute = out + (size_t)e * N * K + (size_t)n0 * K + k0;
    int t = threadIdx.x;
    int lr = t >> 4;
    int lc = (t & 15) * 4;
    #pragma unroll
    for (int i = 0; i < 4; ++i) {
        float4 v = *(const float4*)(ine + (size_t)(i * 16 + lr) * N + lc);
        tile[i * 16 + lr][lc + 0] = v.x;
        tile[i * 16 + lr][lc + 1] = v.y;
        tile[i * 16 + lr][lc + 2] = v.z;
        tile[i * 16 + lr][lc + 3] = v.w;
    }
    __syncthreads();
    int nr = t >> 3;
    int kg = (t & 7) * 8;
    #pragma unroll
    for (int j = 0; j < 2; ++j) {
        int n = j * 32 + nr;
        ushort_t o[8];
        #pragma unroll
        for (int m = 0; m < 8; ++m) o[m] = f2bf(tile[kg + m][n]);
        *(uint4*)(oute + (size_t)n * K + kg) = *(const uint4*)o;
    }
}

// ============ grouped GEMM: 256x256, BK=64, 8-phase, tail-reads, published staging ============
// Single barrier/phase. Phase = [MFMA on frags from prev tail][stage][VW?][ds_reads for next][bar].
// CROSS-WAVE RAW protocol (round-7 fix): a staged unit is readable only after EVERY wave's
// vmcnt confirming that stage + one barrier. Stage order gives each unit >=3 phases of lead:
//   ph1:A00  ph2:B00  ph3:B01+VW6  ph4:A01+RD(A10,B10)  ph5:A10  ph6:B10  ph7:B11+VW6  ph8:A11+RD(A00,B00)
// VW6@ph3 confirms prev-iter {A10,B10,B11,A11} -> published end-ph3 -> covers ph4/ph5/ph6 reads.
// VW6@ph7 confirms this-iter {A00,B00,B01,A01} -> published end-ph7 -> covers ph8/ph1/ph2 reads.
// WAR: every stage is >=1 barrier after its region's last ds_read. Final iter: VW0 at f3, no stages.
// Offsets: each aOff/bOff used twice per iter (buf0 even-kt, buf1 odd-kt), +128B per use.

#define RD_A(BUF, MH) do {                                                        \
    _Pragma("unroll") for (int mi = 0; mi < 4; ++mi) {                            \
        areg[mi][0] = *(const short8*)(pA0 + (BUF)*16384 + (MH)*4096 + mi*1024);  \
        areg[mi][1] = *(const short8*)(pA1 + (BUF)*16384 + (MH)*4096 + mi*1024);  \
    }                                                                             \
} while (0)

#define RD_B(DST, BUF, NH) do {                                                   \
    _Pragma("unroll") for (int ni = 0; ni < 2; ++ni) {                            \
        DST[ni][0] = *(const short8*)(pB0 + (BUF)*16384 + (NH)*2048 + ni*1024);   \
        DST[ni][1] = *(const short8*)(pB1 + (BUF)*16384 + (NH)*2048 + ni*1024);   \
    }                                                                             \
} while (0)

#define MM(BR, MH, NH) do {                                                       \
    __builtin_amdgcn_s_setprio(1);                                                \
    _Pragma("unroll") for (int mi = 0; mi < 4; ++mi)                              \
    _Pragma("unroll") for (int ni = 0; ni < 2; ++ni)                              \
    _Pragma("unroll") for (int ks = 0; ks < 2; ++ks)                              \
      acc[(MH)*4 + mi][(NH)*2 + ni] = __builtin_amdgcn_mfma_f32_16x16x32_bf16(    \
          areg[mi][ks], BR[ni][ks], acc[(MH)*4 + mi][(NH)*2 + ni], 0, 0, 0);      \
    __builtin_amdgcn_s_setprio(0);                                                \
} while (0)

#define PH(MH, NH, BR, TAIL) do { MM(BR, MH, NH); TAIL; __builtin_amdgcn_s_barrier(); } while (0)

#define VW6 asm volatile("s_waitcnt vmcnt(6)" ::: "memory")
#define VW0 asm volatile("s_waitcnt vmcnt(0)" ::: "memory")

template<bool GATHER, bool GELU_ACT>
__global__ __launch_bounds__(512, 2) void moe_gemm8(
    const ushort_t* __restrict__ Ah,
    const ushort_t* __restrict__ BT,
    const float* __restrict__ bias,
    ushort_t* __restrict__ C,
    const int* __restrict__ cnt, const int* __restrict__ basep,
    const int* __restrict__ rowinfo,
    int Ncols, int K)
{
    const int e = blockIdx.z;
    const int cnte = cnt[e];
    const int mt = blockIdx.y;
    if (mt * 256 >= cnte) return;
    const int base_e = basep[e];
    const int row0 = base_e + mt * 256;
    const int col0 = blockIdx.x * 256;

    __shared__ __attribute__((aligned(16))) ushort_t SMEM[2][2][256][64]; // 128 KB

    const int t = threadIdx.x;
    const int lane = t & 63;
    const int wv = t >> 6;
    const int wm = wv >> 2;
    const int wn = wv & 3;
    const int l15 = lane & 15, lhi = lane >> 4;
    const int key = l15 & 7;
    const int lr8 = lane >> 3;
    const int sl  = (lane & 7) ^ lr8;

    const int slot0 = (lhi ^ key) * 8;
    const int slot1 = ((4 + lhi) ^ key) * 8;
    const ushort_t* pA0 = &SMEM[0][0][wm * 128 + l15][slot0];
    const ushort_t* pA1 = &SMEM[0][0][wm * 128 + l15][slot1];
    const ushort_t* pB0 = &SMEM[1][0][wn * 64 + l15][slot0];
    const ushort_t* pB1 = &SMEM[1][0][wn * 64 + l15][slot1];

    uint32_t aOff[2][2], bOff[2][2];
    #pragma unroll
    for (int mh = 0; mh < 2; ++mh)
        #pragma unroll
        for (int c = 0; c < 2; ++c) {
            int tr = mh * 64 + wv * 8 + lr8 + c * 128;
            int gr = row0 + tr; if (gr > TOTROW - 1) gr = TOTROW - 1;
            uint32_t rowid = GATHER ? (uint32_t)rowinfo[gr] : (uint32_t)gr;
            aOff[mh][c] = rowid * (uint32_t)(K * 2) + sl * 16;
        }
    #pragma unroll
    for (int nh = 0; nh < 2; ++nh)
        #pragma unroll
        for (int c = 0; c < 2; ++c) {
            int tr = (wv >> 2) * 64 + nh * 32 + (wv & 3) * 8 + lr8 + c * 128;
            bOff[nh][c] = ((uint32_t)e * Ncols + col0 + tr) * (uint32_t)(K * 2) + sl * 16;
        }

    const int arb = wv * 8;
    const int brb = (wv >> 2) * 64 + (wv & 3) * 8;

    auto stageA = [&](int buf, int mh) {
        gload_lds16((const char*)Ah + aOff[mh][0], (void*)&SMEM[0][buf][mh * 64 + arb][0]);
        gload_lds16((const char*)Ah + aOff[mh][1], (void*)&SMEM[0][buf][128 + mh * 64 + arb][0]);
        aOff[mh][0] += 128; aOff[mh][1] += 128;
    };
    auto stageB = [&](int buf, int nh) {
        gload_lds16((const char*)BT + bOff[nh][0], (void*)&SMEM[1][buf][nh * 32 + brb][0]);
        gload_lds16((const char*)BT + bOff[nh][1], (void*)&SMEM[1][buf][128 + nh * 32 + brb][0]);
        bOff[nh][0] += 128; bOff[nh][1] += 128;
    };

    f32x4 acc[8][4];
    #pragma unroll
    for (int i = 0; i < 8; ++i)
        #pragma unroll
        for (int j = 0; j < 4; ++j)
            acc[i][j] = (f32x4){0.f, 0.f, 0.f, 0.f};

    short8 areg[4][2], breg0[2][2], breg1[2][2];

    const int KT = K / 64;
    const int NIT = KT / 2;

    // prologue: stage ALL 8 units (kt0 -> buf0, kt1 -> buf1); each offset pair used
    // in buf0-then-buf1 order so the +128B auto-increment stays in sync.
    stageA(0, 0); stageB(0, 0); stageB(0, 1); stageA(0, 1);
    stageA(1, 0); stageB(1, 0); stageB(1, 1); stageA(1, 1);
    VW0;                              // own 16 loads landed
    __builtin_amdgcn_s_barrier();     // published across waves
    RD_A(0, 0); RD_B(breg0, 0, 0);    // frags for ph1

    for (int i2 = 0; i2 < NIT - 1; ++i2) {
        /*ph1*/ PH(0, 0, breg0, { stageA(0, 0); RD_B(breg1, 0, 1); });
        /*ph2*/ PH(0, 1, breg1, { stageB(0, 0); RD_A(0, 1); });
        /*ph3*/ PH(1, 1, breg1, { stageB(0, 1); VW6; });
        /*ph4*/ PH(1, 0, breg0, { stageA(0, 1); RD_A(1, 0); RD_B(breg0, 1, 0); });
        /*ph5*/ PH(0, 0, breg0, { stageA(1, 0); RD_B(breg1, 1, 1); });
        /*ph6*/ PH(0, 1, breg1, { stageB(1, 0); RD_A(1, 1); });
        /*ph7*/ PH(1, 1, breg1, { stageB(1, 1); VW6; });
        /*ph8*/ PH(1, 0, breg0, { stageA(1, 1); RD_A(0, 0); RD_B(breg0, 0, 0); });
    }
    {   // final iteration: no staging; single full drain at f3
        /*f1*/ PH(0, 0, breg0, { RD_B(breg1, 0, 1); });
        /*f2*/ PH(0, 1, breg1, { RD_A(0, 1); });
        /*f3*/ PH(1, 1, breg1, { VW0; });
        /*f4*/ PH(1, 0, breg0, { RD_A(1, 0); RD_B(breg0, 1, 0); });
        /*f5*/ PH(0, 0, breg0, { RD_B(breg1, 1, 1); });
        /*f6*/ PH(0, 1, breg1, { RD_A(1, 1); });
        /*f7*/ PH(1, 1, breg1, { });
        /*f8*/ MM(breg0, 1, 0);   // no trailing barrier; no LDS frag reads after f6
    }

    // ---- epilogue: acc -> chunk-XOR-swizzled LDS C-tile -> coalesced stores ----
    ushort_t* ctile = &SMEM[0][0][0][0];
    #pragma unroll
    for (int n = 0; n < 4; ++n) {
        int c = wn * 64 + n * 16 + l15;
        float bv = bias[e * Ncols + col0 + c];
        #pragma unroll
        for (int m = 0; m < 8; ++m) {
            #pragma unroll
            for (int q = 0; q < 4; ++q) {
                int r = wm * 128 + m * 16 + lhi * 4 + q;
                float v = acc[m][n][q] + bv;
                if (GELU_ACT) v = gelu_f(v);
                ctile[r * 256 + ((c >> 3) ^ ((r & 7) << 2)) * 8 + (c & 7)] = f2bf(v);
            }
        }
    }
    __syncthreads();
    {
        int rr = t >> 2;
        int ch0 = t & 3;
        #pragma unroll
        for (int pass = 0; pass < 2; ++pass) {
            int r = pass * 128 + rr;
            int rl = mt * 256 + r;
            if (rl < cnte) {
                size_t gbase = (size_t)(base_e + rl) * Ncols + col0;
                #pragma unroll
                for (int i = 0; i < 8; ++i) {
                    int ch = ch0 + i * 4;
                    uint4 v = *(const uint4*)&ctile[r * 256 + ((ch ^ ((r & 7) << 2)) * 8)];
                    *(uint4*)&C[gbase + ch * 8] = v;
                }
            }
        }
    }
}

// ---------------- combine: out[n] = 0.5*(Y[r1] + Y[r2]) ----------------
__global__ __launch_bounds__(256) void combine_kernel(
    const ushort_t* __restrict__ Y, const int* __restrict__ token_rows,
    float* __restrict__ out)
{
    int n = blockIdx.x;
    int t = threadIdx.x;
    int r1 = token_rows[n * 2 + 0], r2 = token_rows[n * 2 + 1];
    const ushort_t* y1 = Y + (size_t)r1 * D_MODEL + t * 4;
    const ushort_t* y2 = Y + (size_t)r2 * D_MODEL + t * 4;
    ushort_t a[4], b[4];
    *(uint2*)a = *(const uint2*)y1;
    *(uint2*)b = *(const uint2*)y2;
    float4 o;
    o.x = 0.5f * (bf2f(a[0]) + bf2f(b[0]));
    o.y = 0.5f * (bf2f(a[1]) + bf2f(b[1]));
    o.z = 0.5f * (bf2f(a[2]) + bf2f(b[2]));
    o.w = 0.5f * (bf2f(a[3]) + bf2f(b[3]));
    *(float4*)(out + (size_t)n * D_MODEL + t * 4) = o;
}

extern "C" void kernel_launch(void* const* d_in, const int* in_sizes, int n_in,
                              void* d_out, int out_size, void* d_ws, size_t ws_size,
                              hipStream_t stream)
{
    const float* x  = (const float*)d_in[0];
    const float* et = (const float*)d_in[1];
    const float* W1 = (const float*)d_in[2];
    const float* b1 = (const float*)d_in[3];
    const float* W2 = (const float*)d_in[4];
    const float* b2 = (const float*)d_in[5];
    const float* W3 = (const float*)d_in[6];
    const float* b3 = (const float*)d_in[7];
    float* out = (float*)d_out;

    char* ws = (char*)d_ws;
    size_t off = 0;
    auto alloc = [&](size_t bytes) -> char* {
        char* p = ws + off;
        off += (bytes + 255) & ~(size_t)255;
        return p;
    };
    int* cnt        = (int*)alloc(NEXP * 4);
    int* basep      = (int*)alloc(NEXP * 4);
    int* cnt2       = (int*)alloc(NEXP * 4);
    int* top2       = (int*)alloc((size_t)NTOK * 2 * 4);
    int* token_rows = (int*)alloc((size_t)NTOK * 2 * 4);
    int* rowinfo    = (int*)alloc((size_t)TOTROW * 4);
    ushort_t* W1T = (ushort_t*)alloc((size_t)NEXP * D_HID * D_MODEL * 2);
    ushort_t* W2T = (ushort_t*)alloc((size_t)NEXP * D_HID * D_HID * 2);
    ushort_t* W3T = (ushort_t*)alloc((size_t)NEXP * D_MODEL * D_HID * 2);
    ushort_t* H1  = (ushort_t*)alloc((size_t)TOTROW * D_HID * 2);
    ushort_t* H2  = (ushort_t*)alloc((size_t)TOTROW * D_HID * 2);
    ushort_t* Yr  = (ushort_t*)alloc((size_t)TOTROW * D_MODEL * 2);
    if (off > ws_size) return; // workspace too small: fail loudly (wrong output)

    // xb (bf16 x) aliases H2: dead until GEMM2 writes H2.
    ushort_t* xb = H2;

    hipMemsetAsync(cnt, 0, NEXP * 4, stream);
    router_kernel<<<NTOK / 4, 256, 0, stream>>>(x, et, cnt, top2);
    scan_kernel<<<1, 64, 0, stream>>>(cnt, basep, cnt2);
    assign_kernel<<<NTOK / 256, 256, 0, stream>>>(top2, basep, cnt2, rowinfo, token_rows);

    convert_x<<<(NTOK * D_MODEL) / 1024, 256, 0, stream>>>(x, xb);

    transpose_kernel<<<dim3(D_HID / 64, D_MODEL / 64, NEXP), 256, 0, stream>>>(W1, W1T, D_MODEL, D_HID);
    transpose_kernel<<<dim3(D_HID / 64, D_HID / 64, NEXP), 256, 0, stream>>>(W2, W2T, D_HID, D_HID);
    transpose_kernel<<<dim3(D_MODEL / 64, D_HID / 64, NEXP), 256, 0, stream>>>(W3, W3T, D_HID, D_MODEL);

    moe_gemm8<true, true><<<dim3(D_HID / 256, 16, NEXP), 512, 0, stream>>>(
        xb, W1T, b1, H1, cnt, basep, rowinfo, D_HID, D_MODEL);
    moe_gemm8<false, true><<<dim3(D_HID / 256, 16, NEXP), 512, 0, stream>>>(
        H1, W2T, b2, H2, cnt, basep, rowinfo, D_HID, D_HID);
    moe_gemm8<false, false><<<dim3(D_MODEL / 256, 16, NEXP), 512, 0, stream>>>(
        H2, W3T, b3, Yr, cnt, basep, rowinfo, D_MODEL, D_HID);

    combine_kernel<<<NTOK, 256, 0, stream>>>(Yr, token_rows, out);
}